// Round 2
// baseline (255.987 us; speedup 1.0000x reference)
//
#include <hip/hip_runtime.h>
#include <hip/hip_bf16.h>

#define BB 64
#define TT 2048
#define DD 256
#define EPSF 1e-7f
#define ROWS 32         // rows per block: halves LDS vs R0 -> ~7 blocks/CU by LDS
#define XS_STRIDE 264   // shorts/row: 528 B = 33*16 B -> 16B-aligned b128 reads, ~2-way banks

typedef __attribute__((ext_vector_type(8))) short v8s;   // 8 x bf16 (4 VGPRs) — MFMA A/B frag
typedef __attribute__((ext_vector_type(4))) float v4f;   // MFMA C/D frag

__device__ __forceinline__ float bf2f(unsigned short u) {
    union { unsigned int i; float f; } c;
    c.i = ((unsigned int)u) << 16;
    return c.f;
}

__device__ __forceinline__ unsigned int pack2_bf16(float a, float b) {
    union { __hip_bfloat162 h; unsigned int u; } c;
    c.h = __float22bfloat162_rn(make_float2(a, b));   // v_cvt_pk_bf16_f32, RNE
    return c.u;
}

// exact identity tanh(x) = 1 - 2/(exp(2x)+1)
__device__ __forceinline__ float tanh_fast(float x) {
    float e = __expf(2.0f * x);
    return 1.0f - 2.0f / (e + 1.0f);
}

// ---------------- kernel 1: W[d][e] (fp32) -> Wt[e][d] (bf16), LDS tile transpose ----------------
__global__ __launch_bounds__(256) void pack_wt(const float* __restrict__ W,
                                               unsigned short* __restrict__ Wt) {
    __shared__ float tile[32][33];
    int bx = blockIdx.x & 7;    // d-tile
    int by = blockIdx.x >> 3;   // e-tile
    int r  = threadIdx.x >> 3;        // 0..31
    int c4 = (threadIdx.x & 7) * 4;   // 0,4,...,28
    float4 v = *(const float4*)(W + (size_t)(bx * 32 + r) * DD + by * 32 + c4);
    tile[r][c4 + 0] = v.x; tile[r][c4 + 1] = v.y;
    tile[r][c4 + 2] = v.z; tile[r][c4 + 3] = v.w;
    __syncthreads();
    float a0 = tile[c4 + 0][r], a1 = tile[c4 + 1][r];
    float a2 = tile[c4 + 2][r], a3 = tile[c4 + 3][r];
    uint2 pp = make_uint2(pack2_bf16(a0, a1), pack2_bf16(a2, a3));
    *(uint2*)(Wt + (size_t)(by * 32 + r) * DD + bx * 32 + c4) = pp;
}

// ---------------- kernel 2: fused, 32 rows/block, 4 waves, nt-split, B double-buffer ---------
// Block = 32 rows, 4 waves. Wave w computes partial e over nt = w*4..w*4+3 for ALL 32 rows
// (2 m-tiles, A cached in regs once), B prefetched (dbuf). Wave stages + nums its own 8 rows.
// NOTE: every wave's den covers all 32 rows (rl = lane&31) -> write ONE copy, not the sum of 4.
__global__ __launch_bounds__(256, 6) void fused_att4(const float* __restrict__ x,
                                                     const unsigned short* __restrict__ Wt,
                                                     const float* __restrict__ bias,
                                                     const float* __restrict__ uw,
                                                     const int* __restrict__ mask,
                                                     float* __restrict__ numpart,
                                                     float* __restrict__ denpart) {
    __shared__ unsigned short xs[ROWS * XS_STRIDE];   // 16896 B, 32 block-rows
    __shared__ float ered[4][ROWS];                   // per-wave e partials (512 B)
    __shared__ float red[4][DD];                      // num merge (4 KB)

    const int tid  = threadIdx.x;
    const int w    = tid >> 6;     // wave 0..3
    const int lane = tid & 63;
    const int quad = lane >> 4;    // 0..3
    const int m    = lane & 15;    // 0..15
    const long R0  = (long)blockIdx.x * ROWS;   // block's first row
    const long Rw  = R0 + w * 8;                // this wave's staging rows

    // hoisted bias/uw for this wave's nt range (n = (w*4+i)*16 + m)
    float bias_r[4], uw_r[4];
#pragma unroll
    for (int i = 0; i < 4; ++i) {
        int n = (w * 4 + i) * 16 + m;
        bias_r[i] = bias[n];
        uw_r[i]   = uw[n];
    }

    // ---- stage this wave's 8 rows into its LDS slice (1 KB coalesced per load)
    {
        const float* gp = x + Rw * DD + lane * 4;
        unsigned short* sp = xs + (size_t)(w * 8) * XS_STRIDE + lane * 4;
#pragma unroll
        for (int r = 0; r < 8; ++r) {
            float4 v = *(const float4*)(gp + (size_t)r * DD);
            uint2 pp = make_uint2(pack2_bf16(v.x, v.y), pack2_bf16(v.z, v.w));
            *(uint2*)(sp + (size_t)r * XS_STRIDE) = pp;
        }
    }
    __syncthreads();

    // ---- e-GEMM: A (2 m-tiles) cached in regs, B double-buffered over this wave's 4 nt
    float esum[2][4];
#pragma unroll
    for (int mt = 0; mt < 2; ++mt)
#pragma unroll
        for (int r = 0; r < 4; ++r) esum[mt][r] = 0.f;

    v8s a0[8], a1[8];
    {
        const unsigned short* ap0 = xs + (size_t)m * XS_STRIDE + quad * 8;
#pragma unroll
        for (int ks = 0; ks < 8; ++ks) {
            a0[ks] = *(const v8s*)(ap0 + ks * 32);
            a1[ks] = *(const v8s*)(ap0 + 16 * XS_STRIDE + ks * 32);
        }
    }
    v8s bbuf[2][8];
    {
        const unsigned short* bp = Wt + (size_t)(w * 64 + m) * DD + quad * 8;
#pragma unroll
        for (int ks = 0; ks < 8; ++ks) bbuf[0][ks] = *(const v8s*)(bp + ks * 32);
    }
#pragma unroll
    for (int i = 0; i < 4; ++i) {
        const int cur = i & 1;
        if (i < 3) {   // prefetch next nt's B while computing on current
            const unsigned short* bp = Wt + (size_t)((w * 4 + i + 1) * 16 + m) * DD + quad * 8;
#pragma unroll
            for (int ks = 0; ks < 8; ++ks) bbuf[cur ^ 1][ks] = *(const v8s*)(bp + ks * 32);
        }
        v4f acc0 = {0.f, 0.f, 0.f, 0.f};
        v4f acc1 = {0.f, 0.f, 0.f, 0.f};
#pragma unroll
        for (int ks = 0; ks < 8; ++ks) {
            acc0 = __builtin_amdgcn_mfma_f32_16x16x32_bf16(a0[ks], bbuf[cur][ks], acc0, 0, 0, 0);
            acc1 = __builtin_amdgcn_mfma_f32_16x16x32_bf16(a1[ks], bbuf[cur][ks], acc1, 0, 0, 0);
        }
#pragma unroll
        for (int r = 0; r < 4; ++r) {
            esum[0][r] += tanh_fast(acc0[r] + bias_r[i]) * uw_r[i];
            esum[1][r] += tanh_fast(acc1[r] + bias_r[i]) * uw_r[i];
        }
    }

    // ---- reduce over 16 n-lanes; m==0 lanes write this wave's e-partials for all 32 rows
#pragma unroll
    for (int o = 1; o < 16; o <<= 1)
#pragma unroll
        for (int mt = 0; mt < 2; ++mt)
#pragma unroll
            for (int r = 0; r < 4; ++r)
                esum[mt][r] += __shfl_xor(esum[mt][r], o, 64);
    if (m == 0) {
#pragma unroll
        for (int mt = 0; mt < 2; ++mt)
#pragma unroll
            for (int r = 0; r < 4; ++r)
                ered[w][mt * 16 + quad * 4 + r] = esum[mt][r];
    }
    __syncthreads();

    // ---- p for all 32 rows (rl = lane&31); den = sum over the 32 rows (identical in all waves)
    const int rl = lane & 31;
    float et = ered[0][rl] + ered[1][rl] + ered[2][rl] + ered[3][rl];
    float p_loc = __expf(et) * (float)mask[R0 + rl];
    float den = p_loc;
#pragma unroll
    for (int o = 1; o < 32; o <<= 1) den += __shfl_xor(den, o, 64);  // sums 32-lane halves

    // this wave's own 8 rows' p via shuffles (source lanes 0..31)
    float p_all[8];
#pragma unroll
    for (int t = 0; t < 8; ++t) p_all[t] = __shfl(p_loc, w * 8 + t, 64);

    // ---- weighted sum over own 8 rows from own LDS slice; lane covers d = lane*4..+3
    float num[4] = {0.f, 0.f, 0.f, 0.f};
    {
        const unsigned short* xp = xs + (size_t)(w * 8) * XS_STRIDE + lane * 4;
#pragma unroll
        for (int t = 0; t < 8; ++t) {
            uint2 xv = *(const uint2*)(xp + (size_t)t * XS_STRIDE);
            float pt = p_all[t];
            num[0] += pt * bf2f((unsigned short)(xv.x & 0xffffu));
            num[1] += pt * bf2f((unsigned short)(xv.x >> 16));
            num[2] += pt * bf2f((unsigned short)(xv.y & 0xffffu));
            num[3] += pt * bf2f((unsigned short)(xv.y >> 16));
        }
    }

    // ---- merge 4 wave-partials, single store per block
    *(float4*)&red[w][lane * 4] = make_float4(num[0], num[1], num[2], num[3]);
    __syncthreads();
    float s = red[0][tid] + red[1][tid] + red[2][tid] + red[3][tid];
    numpart[(size_t)blockIdx.x * DD + tid] = s;
    if (tid == 0) denpart[blockIdx.x] = den;   // wave 0's den already covers all 32 rows
}

// ---------------- kernel 3: out[b][d] = sum_c num[b*64+c][d] / (sum_c den[b*64+c] + EPS) ------
__global__ __launch_bounds__(256) void finalize(const float* __restrict__ numpart,
                                                const float* __restrict__ denpart,
                                                float* __restrict__ out) {
    __shared__ float4 part[4][64];
    int b = blockIdx.x, t = threadIdx.x;
    int d4 = t & 63;        // float4 index over 256 d
    int cq = t >> 6;        // chunk-quarter (16 chunks each)
    float4 s = make_float4(0.f, 0.f, 0.f, 0.f);
    const float* np = numpart + ((size_t)b * 64 + (size_t)cq * 16) * DD + d4 * 4;
#pragma unroll
    for (int c = 0; c < 16; ++c) {
        float4 v = *(const float4*)(np + (size_t)c * DD);
        s.x += v.x; s.y += v.y; s.z += v.z; s.w += v.w;
    }
    part[cq][d4] = s;
    float dp = (t < 64) ? denpart[b * 64 + t] : 0.f;
    __syncthreads();
    if (t < 64) {   // wave 0: reduce den across 64 lanes, merge 4 quarters, store
#pragma unroll
        for (int o = 1; o < 64; o <<= 1) dp += __shfl_xor(dp, o, 64);
        float4 p0 = part[0][t], p1 = part[1][t], p2 = part[2][t], p3 = part[3][t];
        float inv = 1.0f / (dp + EPSF);
        float4 r;
        r.x = (p0.x + p1.x + p2.x + p3.x) * inv;
        r.y = (p0.y + p1.y + p2.y + p3.y) * inv;
        r.z = (p0.z + p1.z + p2.z + p3.z) * inv;
        r.w = (p0.w + p1.w + p2.w + p3.w) * inv;
        *(float4*)(out + (size_t)b * DD + t * 4) = r;
    }
}

extern "C" void kernel_launch(void* const* d_in, const int* in_sizes, int n_in,
                              void* d_out, int out_size, void* d_ws, size_t ws_size,
                              hipStream_t stream) {
    const float* x    = (const float*)d_in[0];  // [64,2048,256] fp32
    const float* W    = (const float*)d_in[1];  // [256,256] fp32
    const float* bias = (const float*)d_in[2];  // [256] fp32
    const float* uw   = (const float*)d_in[3];  // [256] fp32
    const int*   mask = (const int*)d_in[4];    // [64,2048] int32
    float*       out  = (float*)d_out;          // [64,256] fp32

    char* ws = (char*)d_ws;
    unsigned short* Wt = (unsigned short*)ws;               // 128 KB bf16 W^T
    float* numpart     = (float*)(ws + 131072);             // 4096*256*4 = 4 MB
    float* denpart     = (float*)(ws + 131072 + 4194304);   // 16 KB

    pack_wt<<<dim3(64), dim3(256), 0, stream>>>(W, Wt);
    fused_att4<<<dim3(4096), dim3(256), 0, stream>>>(x, Wt, bias, uw, mask, numpart, denpart);
    finalize<<<dim3(64), dim3(256), 0, stream>>>(numpart, denpart, out);
}

// Round 3
// 232.157 us; speedup vs baseline: 1.1026x; 1.1026x over previous
//
#include <hip/hip_runtime.h>
#include <hip/hip_bf16.h>

#define BB 64
#define TT 2048
#define DD 256
#define EPSF 1e-7f
#define ROWS 32         // rows per block
#define XS_STRIDE 264   // shorts/row: 528 B = 33*16 B -> 16B-aligned b128 reads

typedef __attribute__((ext_vector_type(8))) short v8s;   // 8 x bf16 (4 VGPRs) — MFMA A/B frag
typedef __attribute__((ext_vector_type(4))) float v4f;   // MFMA C/D frag

__device__ __forceinline__ float bf2f(unsigned short u) {
    union { unsigned int i; float f; } c;
    c.i = ((unsigned int)u) << 16;
    return c.f;
}

__device__ __forceinline__ unsigned int pack2_bf16(float a, float b) {
    union { __hip_bfloat162 h; unsigned int u; } c;
    c.h = __float22bfloat162_rn(make_float2(a, b));   // v_cvt_pk_bf16_f32, RNE
    return c.u;
}

// exact identity tanh(x) = 1 - 2/(exp(2x)+1)
__device__ __forceinline__ float tanh_fast(float x) {
    float e = __expf(2.0f * x);
    return 1.0f - 2.0f / (e + 1.0f);
}

__device__ __forceinline__ unsigned short f2bf_rn(float f) {
    union { __hip_bfloat16 h; unsigned short u; } c;
    c.h = __float2bfloat16(f);
    return c.u;
}

// ---------------- kernel 1: W[k][n] (fp32) -> Wt in MFMA-FRAGMENT order (bf16) ----------------
// Layout: Wt[(((nt*8 + ks)*16 + m)*4 + quad)*8 + j] = bf16(W[k][n])
//   with n = nt*16 + m, k = quad*8 + ks*32 + j.
// For each (nt,ks) the 64 lanes (quad,m) then read one CONTIGUOUS 1 KB segment (coalesced).
__global__ __launch_bounds__(256) void pack_wt_frag(const float* __restrict__ W,
                                                    unsigned short* __restrict__ Wt) {
    int idx = blockIdx.x * 256 + threadIdx.x;   // 0..65535
    int j    = idx & 7;
    int quad = (idx >> 3) & 3;
    int m    = (idx >> 5) & 15;
    int ks   = (idx >> 9) & 7;
    int nt   = idx >> 12;
    int n = nt * 16 + m;
    int k = quad * 8 + ks * 32 + j;
    Wt[idx] = f2bf_rn(W[(size_t)k * DD + n]);
}

// ---------------- kernel 2: fused, 32 rows/block, 4 waves, nt-split, B double-buffer ---------
// Block = 32 rows, 4 waves. Wave w computes partial e over nt = w*4..w*4+3 for ALL 32 rows
// (2 m-tiles, A cached in regs once), B prefetched (dbuf), B loads COALESCED via frag-order Wt.
__global__ __launch_bounds__(256, 6) void fused_att5(const float* __restrict__ x,
                                                     const unsigned short* __restrict__ Wt,
                                                     const float* __restrict__ bias,
                                                     const float* __restrict__ uw,
                                                     const int* __restrict__ mask,
                                                     float* __restrict__ numpart,
                                                     float* __restrict__ denpart) {
    __shared__ unsigned short xs[ROWS * XS_STRIDE];   // 16896 B
    __shared__ float ered[4][ROWS];                   // per-wave e partials
    __shared__ float red[4][DD];                      // num merge

    const int tid  = threadIdx.x;
    const int w    = tid >> 6;     // wave 0..3
    const int lane = tid & 63;
    const int quad = lane >> 4;    // 0..3
    const int m    = lane & 15;    // 0..15
    const long R0  = (long)blockIdx.x * ROWS;   // block's first row
    const long Rw  = R0 + w * 8;                // this wave's staging rows

    // per-lane base into frag-ordered Wt: fragment slot (m*4+quad)*8 shorts
    const size_t blane = (size_t)((m * 4 + quad) * 8);

    // hoisted bias/uw for this wave's nt range (n = (w*4+i)*16 + m)
    float bias_r[4], uw_r[4];
#pragma unroll
    for (int i = 0; i < 4; ++i) {
        int n = (w * 4 + i) * 16 + m;
        bias_r[i] = bias[n];
        uw_r[i]   = uw[n];
    }

    // ---- stage this wave's 8 rows into its LDS slice (1 KB coalesced per load)
    {
        const float* gp = x + Rw * DD + lane * 4;
        unsigned short* sp = xs + (size_t)(w * 8) * XS_STRIDE + lane * 4;
#pragma unroll
        for (int r = 0; r < 8; ++r) {
            float4 v = *(const float4*)(gp + (size_t)r * DD);
            uint2 pp = make_uint2(pack2_bf16(v.x, v.y), pack2_bf16(v.z, v.w));
            *(uint2*)(sp + (size_t)r * XS_STRIDE) = pp;
        }
    }
    __syncthreads();

    // ---- e-GEMM: A (2 m-tiles) cached in regs, B double-buffered over this wave's 4 nt
    float esum[2][4];
#pragma unroll
    for (int mt = 0; mt < 2; ++mt)
#pragma unroll
        for (int r = 0; r < 4; ++r) esum[mt][r] = 0.f;

    v8s a0[8], a1[8];
    {
        const unsigned short* ap0 = xs + (size_t)m * XS_STRIDE + quad * 8;
#pragma unroll
        for (int ks = 0; ks < 8; ++ks) {
            a0[ks] = *(const v8s*)(ap0 + ks * 32);
            a1[ks] = *(const v8s*)(ap0 + 16 * XS_STRIDE + ks * 32);
        }
    }
    v8s bbuf[2][8];
    {
        const unsigned short* bp = Wt + (size_t)(w * 4) * 4096 + blane;
#pragma unroll
        for (int ks = 0; ks < 8; ++ks) bbuf[0][ks] = *(const v8s*)(bp + ks * 512);
    }
#pragma unroll
    for (int i = 0; i < 4; ++i) {
        const int cur = i & 1;
        if (i < 3) {   // prefetch next nt's B while computing on current (coalesced 1KB loads)
            const unsigned short* bp = Wt + (size_t)(w * 4 + i + 1) * 4096 + blane;
#pragma unroll
            for (int ks = 0; ks < 8; ++ks) bbuf[cur ^ 1][ks] = *(const v8s*)(bp + ks * 512);
        }
        v4f acc0 = {0.f, 0.f, 0.f, 0.f};
        v4f acc1 = {0.f, 0.f, 0.f, 0.f};
#pragma unroll
        for (int ks = 0; ks < 8; ++ks) {
            acc0 = __builtin_amdgcn_mfma_f32_16x16x32_bf16(a0[ks], bbuf[cur][ks], acc0, 0, 0, 0);
            acc1 = __builtin_amdgcn_mfma_f32_16x16x32_bf16(a1[ks], bbuf[cur][ks], acc1, 0, 0, 0);
        }
#pragma unroll
        for (int r = 0; r < 4; ++r) {
            esum[0][r] += tanh_fast(acc0[r] + bias_r[i]) * uw_r[i];
            esum[1][r] += tanh_fast(acc1[r] + bias_r[i]) * uw_r[i];
        }
    }

    // ---- reduce over 16 n-lanes; m==0 lanes write this wave's e-partials for all 32 rows
#pragma unroll
    for (int o = 1; o < 16; o <<= 1)
#pragma unroll
        for (int mt = 0; mt < 2; ++mt)
#pragma unroll
            for (int r = 0; r < 4; ++r)
                esum[mt][r] += __shfl_xor(esum[mt][r], o, 64);
    if (m == 0) {
#pragma unroll
        for (int mt = 0; mt < 2; ++mt)
#pragma unroll
            for (int r = 0; r < 4; ++r)
                ered[w][mt * 16 + quad * 4 + r] = esum[mt][r];
    }
    __syncthreads();

    // ---- p for all 32 rows (rl = lane&31); den = sum over the 32 rows (identical in all waves)
    const int rl = lane & 31;
    float et = ered[0][rl] + ered[1][rl] + ered[2][rl] + ered[3][rl];
    float p_loc = __expf(et) * (float)mask[R0 + rl];
    float den = p_loc;
#pragma unroll
    for (int o = 1; o < 32; o <<= 1) den += __shfl_xor(den, o, 64);

    // this wave's own 8 rows' p via shuffles (source lanes 0..31)
    float p_all[8];
#pragma unroll
    for (int t = 0; t < 8; ++t) p_all[t] = __shfl(p_loc, w * 8 + t, 64);

    // ---- weighted sum over own 8 rows from own LDS slice; lane covers d = lane*4..+3
    float num[4] = {0.f, 0.f, 0.f, 0.f};
    {
        const unsigned short* xp = xs + (size_t)(w * 8) * XS_STRIDE + lane * 4;
#pragma unroll
        for (int t = 0; t < 8; ++t) {
            uint2 xv = *(const uint2*)(xp + (size_t)t * XS_STRIDE);
            float pt = p_all[t];
            num[0] += pt * bf2f((unsigned short)(xv.x & 0xffffu));
            num[1] += pt * bf2f((unsigned short)(xv.x >> 16));
            num[2] += pt * bf2f((unsigned short)(xv.y & 0xffffu));
            num[3] += pt * bf2f((unsigned short)(xv.y >> 16));
        }
    }

    // ---- merge 4 wave-partials, single store per block
    *(float4*)&red[w][lane * 4] = make_float4(num[0], num[1], num[2], num[3]);
    __syncthreads();
    float s = red[0][tid] + red[1][tid] + red[2][tid] + red[3][tid];
    numpart[(size_t)blockIdx.x * DD + tid] = s;
    if (tid == 0) denpart[blockIdx.x] = den;   // wave 0's den covers all 32 rows
}

// ---------------- kernel 3: out[b][d] = sum_c num[b*64+c][d] / (sum_c den[b*64+c] + EPS) ------
__global__ __launch_bounds__(256) void finalize(const float* __restrict__ numpart,
                                                const float* __restrict__ denpart,
                                                float* __restrict__ out) {
    __shared__ float4 part[4][64];
    int b = blockIdx.x, t = threadIdx.x;
    int d4 = t & 63;        // float4 index over 256 d
    int cq = t >> 6;        // chunk-quarter (16 chunks each)
    float4 s = make_float4(0.f, 0.f, 0.f, 0.f);
    const float* np = numpart + ((size_t)b * 64 + (size_t)cq * 16) * DD + d4 * 4;
#pragma unroll
    for (int c = 0; c < 16; ++c) {
        float4 v = *(const float4*)(np + (size_t)c * DD);
        s.x += v.x; s.y += v.y; s.z += v.z; s.w += v.w;
    }
    part[cq][d4] = s;
    float dp = (t < 64) ? denpart[b * 64 + t] : 0.f;
    __syncthreads();
    if (t < 64) {
#pragma unroll
        for (int o = 1; o < 64; o <<= 1) dp += __shfl_xor(dp, o, 64);
        float4 p0 = part[0][t], p1 = part[1][t], p2 = part[2][t], p3 = part[3][t];
        float inv = 1.0f / (dp + EPSF);
        float4 r;
        r.x = (p0.x + p1.x + p2.x + p3.x) * inv;
        r.y = (p0.y + p1.y + p2.y + p3.y) * inv;
        r.z = (p0.z + p1.z + p2.z + p3.z) * inv;
        r.w = (p0.w + p1.w + p2.w + p3.w) * inv;
        *(float4*)(out + (size_t)b * DD + t * 4) = r;
    }
}

extern "C" void kernel_launch(void* const* d_in, const int* in_sizes, int n_in,
                              void* d_out, int out_size, void* d_ws, size_t ws_size,
                              hipStream_t stream) {
    const float* x    = (const float*)d_in[0];  // [64,2048,256] fp32
    const float* W    = (const float*)d_in[1];  // [256,256] fp32
    const float* bias = (const float*)d_in[2];  // [256] fp32
    const float* uw   = (const float*)d_in[3];  // [256] fp32
    const int*   mask = (const int*)d_in[4];    // [64,2048] int32
    float*       out  = (float*)d_out;          // [64,256] fp32

    char* ws = (char*)d_ws;
    unsigned short* Wt = (unsigned short*)ws;               // 128 KB bf16 W in frag order
    float* numpart     = (float*)(ws + 131072);             // 4096*256*4 = 4 MB
    float* denpart     = (float*)(ws + 131072 + 4194304);   // 16 KB

    pack_wt_frag<<<dim3(256), dim3(256), 0, stream>>>(W, Wt);
    fused_att5<<<dim3(4096), dim3(256), 0, stream>>>(x, Wt, bias, uw, mask, numpart, denpart);
    finalize<<<dim3(64), dim3(256), 0, stream>>>(numpart, denpart, out);
}